// Round 7
// baseline (210.716 us; speedup 1.0000x reference)
//
#include <hip/hip_runtime.h>

#define D_IN   2048
#define D_OUT  2048
#define N_TOK  1024
#define N_B    8
#define RANK   16
#define KS     16                 // K-split
#define ICH    (D_IN / KS)        // 128 i per block, two 64-i chunks
// SCALING = ALPHA/RANK = 1.0 -> omitted
// d_ws: float W[KS][N_B][N_TOK][RANK] = 8 MB partials (assumes ws_size >= 8 MB)

__device__ __forceinline__ float dot4(float4 a, float4 b) {
    return a.x * b.x + a.y * b.y + a.z * b.z + a.w * b.w;
}

// ---------------- K1: lane = token. W[ks][b][t][r] = sum_{i in chunk} x*B ----------------
// B addresses are wave-uniform (no threadIdx) -> scalar/broadcast loads.
// x staged [64 tok][64 i] in LDS with XOR swizzle (seg ^= row&15) on write AND read:
// conflict-free (8 words/bank = transaction floor) both directions.
__global__ __launch_bounds__(64)
void lora_bx_v6(const float* __restrict__ x,
                const float* __restrict__ B,
                const int* __restrict__ ids,
                float* __restrict__ W) {
    __shared__ __align__(16) float xs[64 * 64];   // 16 KB

    const int tile = blockIdx.x;      // 16 token-tiles per batch
    const int ks   = blockIdx.y;      // 16 K-slices
    const int b    = blockIdx.z;
    const int aid  = ids[b];
    const int l    = (int)threadIdx.x;   // 0..63 = token row

    const float* __restrict__ xb = x + ((size_t)b * N_TOK + tile * 64) * D_IN + ks * ICH;
    const float* __restrict__ Bq = B + (size_t)aid * RANK * D_IN + ks * ICH;

    float acc[RANK];
    #pragma unroll
    for (int r = 0; r < RANK; ++r) acc[r] = 0.f;

    #pragma unroll
    for (int c = 0; c < 2; ++c) {                 // two 64-i chunks
        const float* xc = xb + c * 64;
        const float* Bc = Bq + c * 64;

        __syncthreads();                          // protect previous chunk's reads
        // ---- stage x[64 rows][64 i], two batches of 8 float4/lane ----
        #pragma unroll
        for (int h = 0; h < 2; ++h) {
            float4 st[8];
            #pragma unroll
            for (int kk = 0; kk < 8; ++kk) {
                const int k   = h * 8 + kk;
                const int row = k * 4 + (l >> 4);
                const int seg = l & 15;
                st[kk] = *reinterpret_cast<const float4*>(&xc[(size_t)row * D_IN + seg * 4]);
            }
            #pragma unroll
            for (int kk = 0; kk < 8; ++kk) {
                const int k   = h * 8 + kk;
                const int row = k * 4 + (l >> 4);
                const int v   = (l & 15) ^ (row & 15);
                *reinterpret_cast<float4*>(&xs[row * 64 + v * 4]) = st[kk];
            }
        }
        __syncthreads();

        // ---- compute: my token row l, all 16 ranks; B is wave-uniform ----
        #pragma unroll
        for (int j = 0; j < 16; ++j) {
            const int v = j ^ (l & 15);
            const float4 xv = *reinterpret_cast<const float4*>(&xs[l * 64 + v * 4]);
            #pragma unroll
            for (int r = 0; r < RANK; ++r) {
                const float4 Bv = *reinterpret_cast<const float4*>(&Bc[(size_t)r * D_IN + j * 4]);
                acc[r] += dot4(xv, Bv);
            }
        }
    }

    float* Wp = W + (((size_t)ks * N_B + b) * N_TOK + tile * 64 + l) * RANK;
    *reinterpret_cast<float4*>(&Wp[0])  = make_float4(acc[0],  acc[1],  acc[2],  acc[3]);
    *reinterpret_cast<float4*>(&Wp[4])  = make_float4(acc[4],  acc[5],  acc[6],  acc[7]);
    *reinterpret_cast<float4*>(&Wp[8])  = make_float4(acc[8],  acc[9],  acc[10], acc[11]);
    *reinterpret_cast<float4*>(&Wp[12]) = make_float4(acc[12], acc[13], acc[14], acc[15]);
}

// ---------------- K2: reduce KS partials, then out = Bx * A^T ----------------
__global__ __launch_bounds__(256, 2)
void lora_out_v6(const float* __restrict__ A,
                 const int* __restrict__ ids,
                 const float* __restrict__ W,
                 float* __restrict__ out) {
    __shared__ __align__(16) float bxs[8][RANK];

    const int tile = blockIdx.x;          // 8-token tile (0..127)
    const int half = blockIdx.y;          // o-half
    const int b    = blockIdx.z;
    const int aid  = ids[b];
    const int tid  = (int)threadIdx.x;

    // phase A: bxs[t][r] = sum_s W[s][b][tile*8+t][r]  (coalesced 512B per s)
    if (tid < 128) {
        const int t = tid >> 4, r = tid & 15;
        const size_t base = ((size_t)b * N_TOK + tile * 8 + t) * RANK + r;
        const size_t sstr = (size_t)N_B * N_TOK * RANK;   // 131072 floats per slice
        float s0 = 0.f, s1 = 0.f, s2 = 0.f, s3 = 0.f;
        #pragma unroll
        for (int s = 0; s < KS; s += 4) {
            s0 += W[(s + 0) * sstr + base];
            s1 += W[(s + 1) * sstr + base];
            s2 += W[(s + 2) * sstr + base];
            s3 += W[(s + 3) * sstr + base];
        }
        bxs[t][r] = (s0 + s1) + (s2 + s3);
    }
    __syncthreads();

    // phase B: thread covers 4 o-rows; A in regs, reused over 8 tokens
    const int o0 = half * 1024 + tid * 4;
    const float* __restrict__ Aa = A + (size_t)aid * D_OUT * RANK;
    float* __restrict__ ob = out + ((size_t)b * N_TOK + tile * 8) * D_OUT;

    float4 Ar[4][4];
    #pragma unroll
    for (int j = 0; j < 4; ++j)
        #pragma unroll
        for (int q = 0; q < 4; ++q)
            Ar[j][q] = *reinterpret_cast<const float4*>(&Aa[(size_t)(o0 + j) * RANK + q * 4]);

    #pragma unroll
    for (int t = 0; t < 8; ++t) {
        const float4 p0 = *reinterpret_cast<const float4*>(&bxs[t][0]);   // broadcast
        const float4 p1 = *reinterpret_cast<const float4*>(&bxs[t][4]);
        const float4 p2 = *reinterpret_cast<const float4*>(&bxs[t][8]);
        const float4 p3 = *reinterpret_cast<const float4*>(&bxs[t][12]);
        float4 res;
        res.x = dot4(Ar[0][0], p0) + dot4(Ar[0][1], p1) + dot4(Ar[0][2], p2) + dot4(Ar[0][3], p3);
        res.y = dot4(Ar[1][0], p0) + dot4(Ar[1][1], p1) + dot4(Ar[1][2], p2) + dot4(Ar[1][3], p3);
        res.z = dot4(Ar[2][0], p0) + dot4(Ar[2][1], p1) + dot4(Ar[2][2], p2) + dot4(Ar[2][3], p3);
        res.w = dot4(Ar[3][0], p0) + dot4(Ar[3][1], p1) + dot4(Ar[3][2], p2) + dot4(Ar[3][3], p3);
        *reinterpret_cast<float4*>(&ob[(size_t)t * D_OUT + o0]) = res;
    }
}

extern "C" void kernel_launch(void* const* d_in, const int* in_sizes, int n_in,
                              void* d_out, int out_size, void* d_ws, size_t ws_size,
                              hipStream_t stream) {
    const float* x   = (const float*)d_in[0];
    const float* A   = (const float*)d_in[1];
    const float* B   = (const float*)d_in[2];
    const int*   ids = (const int*)d_in[3];
    float* out = (float*)d_out;
    float* W   = (float*)d_ws;   // 8 MB

    dim3 g1(N_TOK / 64, KS, N_B);     // (16, 16, 8) = 2048 one-wave blocks
    lora_bx_v6<<<g1, 64, 0, stream>>>(x, B, ids, W);

    dim3 g2(N_TOK / 8, 2, N_B);       // (128, 2, 8) = 2048 blocks
    lora_out_v6<<<g2, 256, 0, stream>>>(A, ids, W, out);
}